// Round 12
// baseline (367.766 us; speedup 1.0000x reference)
//
#include <hip/hip_runtime.h>
#include <hip/hip_bf16.h>
#include <math.h>

typedef short s8 __attribute__((ext_vector_type(8)));   // 8 bf16 in 4 VGPRs
typedef float f4 __attribute__((ext_vector_type(4)));   // MFMA 16x16 acc
typedef unsigned short ushort_t;

__device__ __forceinline__ float fexp2f(float x) { return __builtin_amdgcn_exp2f(x); }
__device__ __forceinline__ float frcpf(float x)  { return __builtin_amdgcn_rcpf(x); }
__device__ __forceinline__ float sigf(float x) {
    return frcpf(1.f + fexp2f(x * -1.44269504f));
}
__device__ __forceinline__ float tanh_f(float x) {
    float e = fexp2f(x * 2.88539008f);
    return 1.f - 2.f * frcpf(e + 1.f);
}
__device__ __forceinline__ unsigned pk2(float a, float b) {
    __hip_bfloat162 r = __float22bfloat162_rn(make_float2(a, b));
    return *(unsigned*)&r;
}
__device__ __forceinline__ float b2f(ushort_t b) {
    return __uint_as_float(((unsigned)b) << 16);
}
__device__ __forceinline__ ushort_t f2b(float f) {
    unsigned u = __float_as_uint(f);
    u = (u + 0x7FFF + ((u >> 16) & 1)) >> 16;
    return (ushort_t)u;
}

// ---------------------------------------------------------------------------
// Convert emb / Wih / Whh / SW^T to bf16 (packed cvt).
// ---------------------------------------------------------------------------
#define EMB_N   6400000          // 50000*128
#define W_N     49152            // 384*128
#define SW_N    16384            // 128*128
#define CVT_N   (EMB_N + 2 * W_N + SW_N)

__global__ __launch_bounds__(256) void cvt_kernel(
    const float* __restrict__ emb, const float* __restrict__ wih,
    const float* __restrict__ whh, const float* __restrict__ sw,
    ushort_t* __restrict__ embb, ushort_t* __restrict__ wihb,
    ushort_t* __restrict__ whhb, ushort_t* __restrict__ swtb)
{
    int i = (blockIdx.x * 256 + threadIdx.x) * 4;
    if (i >= CVT_N) return;
    if (i < EMB_N) {
        float4 v = *(const float4*)(emb + i);
        uint2 o; o.x = pk2(v.x, v.y); o.y = pk2(v.z, v.w);
        *(uint2*)(embb + i) = o;
    } else if (i < EMB_N + W_N) {
        int j = i - EMB_N;
        float4 v = *(const float4*)(wih + j);
        uint2 o; o.x = pk2(v.x, v.y); o.y = pk2(v.z, v.w);
        *(uint2*)(wihb + j) = o;
    } else if (i < EMB_N + 2 * W_N) {
        int j = i - EMB_N - W_N;
        float4 v = *(const float4*)(whh + j);
        uint2 o; o.x = pk2(v.x, v.y); o.y = pk2(v.z, v.w);
        *(uint2*)(whhb + j) = o;
    } else {
        int j = i - EMB_N - 2 * W_N;
        int f = j >> 7, e0 = j & 127;
        uint2 o;
        o.x = pk2(sw[(e0 + 0) * 128 + f], sw[(e0 + 1) * 128 + f]);
        o.y = pk2(sw[(e0 + 2) * 128 + f], sw[(e0 + 3) * 128 + f]);
        *(uint2*)(swtb + j) = o;         // SWt[f][e]
    }
}

// ---------------------------------------------------------------------------
// WHOLE-TREE kernel. The computation is batch-separable: GRU rows, sibling
// attention (softmax over the 4 children at the same batch index), and the
// final max are all independent per batch element. Grid = 256 blocks = one
// batch element each; all 6 levels run inside the block with __syncthreads
// only (no grid sync, no intermediate kernel launches).
//
// Block = 1024 thr = 16 waves. Wave w: cg = w&7 (gate-col group cg*16..+15),
// mh = w>>3 (which half of the M-tiles). Per level, nodes are processed in
// chunks of <=128 node-rows: stage x (+h0) -> GRU (r9-verified barrier-free
// body, writes hnew) -> running max (registers) + attention -> parent h0
// written to a tiny per-batch global slice (64KB max, L2-resident).
// Sub-16 levels (L1 nodes=4, root=1) pad rows by clamping the node index:
// pad rows are duplicates of valid rows, so max/attn stay exact.
// LDS = 113.7 KB -> 1 block/CU, 16 waves (50% occupancy).
// ---------------------------------------------------------------------------
__global__ __launch_bounds__(1024, 1) void tree_kernel(
    const int* __restrict__ tokens, const ushort_t* __restrict__ embb,
    const ushort_t* __restrict__ wihb, const ushort_t* __restrict__ whhb,
    const float* __restrict__ bih, const float* __restrict__ bhh,
    const ushort_t* __restrict__ swt, const float* __restrict__ sb,
    const float* __restrict__ cw,
    ushort_t* __restrict__ g4, ushort_t* __restrict__ g3,
    ushort_t* __restrict__ g2, ushort_t* __restrict__ g1,
    ushort_t* __restrict__ g0buf, float* __restrict__ out)
{
    __shared__ ushort_t xs[128 * 136];
    __shared__ ushort_t hs[128 * 136];
    __shared__ ushort_t hnew[128 * 136];
    __shared__ float scp[8][128];
    __shared__ float sc[128];
    __shared__ float al[4][32];
    __shared__ float smax[8][128];

    const int t = threadIdx.x;
    const int b = blockIdx.x;                 // batch element
    const int lane = t & 63, w = t >> 6;      // 16 waves
    const int cg = w & 7, mh = w >> 3;
    const int quad = lane >> 4, l15 = lane & 15;
    const int gA = cg * 16 + l15;             // weight row this lane supplies
    const int g0 = cg * 16 + quad * 4;        // epilogue col group

    // weights (compiler keeps/reloads from L1 as it sees fit — measured OK)
    s8 bwi[3][4], bwh[3][4];
    #pragma unroll
    for (int gm = 0; gm < 3; ++gm) {
        const ushort_t* wp = wihb + (size_t)(gm * 128 + gA) * 128 + quad * 8;
        #pragma unroll
        for (int s = 0; s < 4; ++s) bwi[gm][s] = *(const s8*)(wp + 32 * s);
        const ushort_t* wp2 = whhb + (size_t)(gm * 128 + gA) * 128 + quad * 8;
        #pragma unroll
        for (int s = 0; s < 4; ++s) bwh[gm][s] = *(const s8*)(wp2 + 32 * s);
    }
    float bR[4], bZ[4], biN[4], bhN[4];
    {
        float4 a = *(const float4*)(bih + g0);
        float4 bb = *(const float4*)(bhh + g0);
        bR[0] = a.x + bb.x; bR[1] = a.y + bb.y; bR[2] = a.z + bb.z; bR[3] = a.w + bb.w;
        float4 c = *(const float4*)(bih + 128 + g0);
        float4 d = *(const float4*)(bhh + 128 + g0);
        bZ[0] = c.x + d.x; bZ[1] = c.y + d.y; bZ[2] = c.z + d.z; bZ[3] = c.w + d.w;
        float4 e = *(const float4*)(bih + 256 + g0);
        float4 f = *(const float4*)(bhh + 256 + g0);
        biN[0] = e.x; biN[1] = e.y; biN[2] = e.z; biN[3] = e.w;
        bhN[0] = f.x; bhN[1] = f.y; bhN[2] = f.z; bhN[3] = f.w;
    }
    s8 bsw[4];
    {
        const ushort_t* wp = swt + (size_t)gA * 128 + quad * 8;
        #pragma unroll
        for (int s = 0; s < 4; ++s) bsw[s] = *(const s8*)(wp + 32 * s);
    }
    float sb4[4], cw4[4];
    {
        float4 a = *(const float4*)(sb + g0);
        float4 bb = *(const float4*)(cw + g0);
        sb4[0] = a.x; sb4[1] = a.y; sb4[2] = a.z; sb4[3] = a.w;
        cw4[0] = bb.x; cw4[1] = bb.y; cw4[2] = bb.z; cw4[3] = bb.w;
    }

    float vmax = -INFINITY;
    const int mcol = t & 127, mrg = t >> 7;   // running-max mapping

    const int nodesA[6] = {1024, 256, 64, 16, 4, 1};
    const int tok0A[6]  = {341, 85, 21, 5, 1, 0};
    ushort_t* houtA[6] = {g4, g3, g2, g1, g0buf, nullptr};
    const ushort_t* h0in = nullptr;

    for (int L = 0; L < 6; ++L) {
        const int nodes = nodesA[L], tok0 = tok0A[L];
        ushort_t* h0out = houtA[L];
        const int nchunks = (nodes + 127) >> 7;
        for (int c = 0; c < nchunks; ++c) {
            const int node0 = c << 7;
            const int vnodes = min(nodes - node0, 128);
            const int R = (vnodes + 15) & ~15;      // pad rows to 16 (clamped dups)
            const int mts = R >> 4;
            const int P = h0out ? (vnodes >> 2) : 0;

            // ---- stage x (+h0): 8 thr/row, 16 shorts each ----
            {
                int lr = t >> 3, ci = (t & 7) * 16;
                if (lr < R) {
                    int node = min(node0 + lr, nodes - 1);   // clamp -> dup rows
                    int tok = tokens[(tok0 + node) * 256 + b];
                    const ushort_t* src = embb + (size_t)tok * 128 + ci;
                    ushort_t* dst = &xs[lr * 136 + ci];
                    *(s8*)dst       = *(const s8*)src;
                    *(s8*)(dst + 8) = *(const s8*)(src + 8);
                    if (h0in) {
                        const ushort_t* hsrc = h0in + ((size_t)node * 256 + b) * 128 + ci;
                        ushort_t* hdst = &hs[lr * 136 + ci];
                        *(s8*)hdst       = *(const s8*)hsrc;
                        *(s8*)(hdst + 8) = *(const s8*)(hsrc + 8);
                    }
                }
            }
            __syncthreads();

            // ---- GRU (barrier-free within phase; wave does its mt-half) ----
            const int half = (mts + 1) >> 1;
            const int m0 = mh * half, m1 = min(mts, m0 + half);
            for (int mt = m0; mt < m1; ++mt) {
                const int row = mt * 16 + l15;
                s8 ax[4], ah[4];
                {
                    const ushort_t* ap = &xs[row * 136 + quad * 8];
                    #pragma unroll
                    for (int s = 0; s < 4; ++s) ax[s] = *(const s8*)(ap + 32 * s);
                    if (h0in) {
                        const ushort_t* hp = &hs[row * 136 + quad * 8];
                        #pragma unroll
                        for (int s = 0; s < 4; ++s) ah[s] = *(const s8*)(hp + 32 * s);
                    }
                }
                f4 accR = (f4)0.f, accZ = (f4)0.f, accN = (f4)0.f, accNh = (f4)0.f;
                #pragma unroll
                for (int s = 0; s < 4; ++s) {
                    accR = __builtin_amdgcn_mfma_f32_16x16x32_bf16(bwi[0][s], ax[s], accR, 0, 0, 0);
                    accZ = __builtin_amdgcn_mfma_f32_16x16x32_bf16(bwi[1][s], ax[s], accZ, 0, 0, 0);
                    accN = __builtin_amdgcn_mfma_f32_16x16x32_bf16(bwi[2][s], ax[s], accN, 0, 0, 0);
                }
                if (h0in) {
                    #pragma unroll
                    for (int s = 0; s < 4; ++s) {
                        accR  = __builtin_amdgcn_mfma_f32_16x16x32_bf16(bwh[0][s], ah[s], accR, 0, 0, 0);
                        accZ  = __builtin_amdgcn_mfma_f32_16x16x32_bf16(bwh[1][s], ah[s], accZ, 0, 0, 0);
                        accNh = __builtin_amdgcn_mfma_f32_16x16x32_bf16(bwh[2][s], ah[s], accNh, 0, 0, 0);
                    }
                }
                float h0v[4] = {0.f, 0.f, 0.f, 0.f};
                if (h0in) {
                    short4 h04 = *(const short4*)&hs[row * 136 + g0];
                    h0v[0] = b2f((ushort_t)h04.x); h0v[1] = b2f((ushort_t)h04.y);
                    h0v[2] = b2f((ushort_t)h04.z); h0v[3] = b2f((ushort_t)h04.w);
                }
                float hv[4];
                #pragma unroll
                for (int r = 0; r < 4; ++r) {
                    float rr = sigf(accR[r] + bR[r]);
                    float zz = sigf(accZ[r] + bZ[r]);
                    float hn = h0in ? (accNh[r] + bhN[r]) : bhN[r];
                    float nn = tanh_f(accN[r] + biN[r] + rr * hn);
                    hv[r] = nn + zz * (h0v[r] - nn);
                }
                uint2 ov; ov.x = pk2(hv[0], hv[1]); ov.y = pk2(hv[2], hv[3]);
                *(uint2*)&hnew[row * 136 + g0] = ov;
            }
            __syncthreads();

            // ---- running max. Stale rows (R<128) hold h from earlier chunks
            // (already maxed -> re-max is a no-op); pad rows are dups. Exact.
            {
                const ushort_t* hp = &hnew[(mrg * 16) * 136 + mcol];
                #pragma unroll 4
                for (int r = 0; r < 16; ++r)
                    vmax = fmaxf(vmax, b2f(hp[r * 136]));
            }

            if (h0out) {
                // ---- attention over 4 consecutive sibling rows ----
                for (int mt = m0; mt < m1; ++mt) {
                    const int crow = mt * 16 + l15;
                    s8 a[4];
                    const ushort_t* ap = &hnew[crow * 136 + quad * 8];
                    #pragma unroll
                    for (int s = 0; s < 4; ++s) a[s] = *(const s8*)(ap + 32 * s);
                    f4 acc = (f4)0.f;
                    #pragma unroll
                    for (int s = 0; s < 4; ++s)
                        acc = __builtin_amdgcn_mfma_f32_16x16x32_bf16(bsw[s], a[s], acc, 0, 0, 0);
                    float part = 0.f;
                    #pragma unroll
                    for (int r = 0; r < 4; ++r)
                        part += tanh_f(acc[r] + sb4[r]) * cw4[r];
                    part += __shfl_xor(part, 16);
                    part += __shfl_xor(part, 32);
                    if (quad == 0) scp[cg][crow] = part;
                }
                __syncthreads();
                if (t < mts * 16) {
                    float s_ = 0.f;
                    #pragma unroll
                    for (int g = 0; g < 8; ++g) s_ += scp[g][t];
                    sc[t] = tanh_f(s_);
                }
                __syncthreads();
                if (t < P) {
                    float s0 = sc[4 * t], s1 = sc[4 * t + 1];
                    float s2 = sc[4 * t + 2], s3 = sc[4 * t + 3];
                    float m = fmaxf(fmaxf(s0, s1), fmaxf(s2, s3));
                    float e0 = fexp2f((s0 - m) * 1.44269504f);
                    float e1 = fexp2f((s1 - m) * 1.44269504f);
                    float e2 = fexp2f((s2 - m) * 1.44269504f);
                    float e3 = fexp2f((s3 - m) * 1.44269504f);
                    float inv = frcpf(e0 + e1 + e2 + e3);
                    al[0][t] = e0 * inv; al[1][t] = e1 * inv;
                    al[2][t] = e2 * inv; al[3][t] = e3 * inv;
                }
                __syncthreads();
                if (t < 16 * P) {
                    int bl = t >> 4, e0 = (t & 15) * 8;
                    float a0 = al[0][bl], a1 = al[1][bl], a2 = al[2][bl], a3 = al[3][bl];
                    s8 c0v = *(const s8*)&hnew[(4 * bl + 0) * 136 + e0];
                    s8 c1v = *(const s8*)&hnew[(4 * bl + 1) * 136 + e0];
                    s8 c2v = *(const s8*)&hnew[(4 * bl + 2) * 136 + e0];
                    s8 c3v = *(const s8*)&hnew[(4 * bl + 3) * 136 + e0];
                    float o[8];
                    #pragma unroll
                    for (int j = 0; j < 8; ++j) {
                        o[j] = a0 * b2f((ushort_t)c0v[j]) + a1 * b2f((ushort_t)c1v[j])
                             + a2 * b2f((ushort_t)c2v[j]) + a3 * b2f((ushort_t)c3v[j]);
                    }
                    uint4 ovv;
                    ovv.x = pk2(o[0], o[1]); ovv.y = pk2(o[2], o[3]);
                    ovv.z = pk2(o[4], o[5]); ovv.w = pk2(o[6], o[7]);
                    size_t pnode = (size_t)((node0 >> 2) + bl);
                    *(uint4*)(h0out + (pnode * 256 + b) * 128 + e0) = ovv;
                }
            }
            __syncthreads();   // hnew/xs/hs safe to reuse next chunk
        }
        h0in = h0out;
    }

    // ---- final reduce of per-thread maxes -> out[b][*] ----
    smax[mrg][mcol] = vmax;
    __syncthreads();
    if (t < 128) {
        float v = smax[0][t];
        #pragma unroll
        for (int rg = 1; rg < 8; ++rg) v = fmaxf(v, smax[rg][t]);
        out[(size_t)b * 128 + t] = v;
    }
}

extern "C" void kernel_launch(void* const* d_in, const int* in_sizes, int n_in,
                              void* d_out, int out_size, void* d_ws, size_t ws_size,
                              hipStream_t stream)
{
    const int*   tokens = (const int*)d_in[0];
    const float* emb    = (const float*)d_in[1];
    const float* Wih    = (const float*)d_in[2];
    const float* Whh    = (const float*)d_in[3];
    const float* bih    = (const float*)d_in[4];
    const float* bhh    = (const float*)d_in[5];
    const float* SW     = (const float*)d_in[6];
    const float* sb     = (const float*)d_in[7];
    const float* cw     = (const float*)d_in[8];
    float* out = (float*)d_out;

    // ws layout (shorts)
    ushort_t* embb = (ushort_t*)d_ws;                        // 12.8 MB
    ushort_t* wihb = embb + (size_t)EMB_N;
    ushort_t* whhb = wihb + W_N;
    ushort_t* swtb = whhb + W_N;
    ushort_t* g4   = swtb + SW_N;                            // 256n x 256b x 128
    ushort_t* g3   = g4 + (size_t)256 * 256 * 128;           // 64n
    ushort_t* g2   = g3 + (size_t)64 * 256 * 128;            // 16n
    ushort_t* g1   = g2 + (size_t)16 * 256 * 128;            // 4n
    ushort_t* g0   = g1 + (size_t)4 * 256 * 128;             // 1n

    cvt_kernel<<<(CVT_N / 4 + 255) / 256, 256, 0, stream>>>(
        emb, Wih, Whh, SW, embb, wihb, whhb, swtb);

    tree_kernel<<<256, 1024, 0, stream>>>(
        tokens, embb, wihb, whhb, bih, bhh, swtb, sb, cw,
        g4, g3, g2, g1, g0, out);
}

// Round 13
// 243.265 us; speedup vs baseline: 1.5118x; 1.5118x over previous
//
#include <hip/hip_runtime.h>
#include <hip/hip_bf16.h>
#include <math.h>

typedef short s8 __attribute__((ext_vector_type(8)));   // 8 bf16 in 4 VGPRs
typedef float f4 __attribute__((ext_vector_type(4)));   // MFMA 16x16 acc
typedef unsigned short ushort_t;

__device__ __forceinline__ float fexp2f(float x) { return __builtin_amdgcn_exp2f(x); }
__device__ __forceinline__ float frcpf(float x)  { return __builtin_amdgcn_rcpf(x); }
__device__ __forceinline__ float sigf(float x) {
    return frcpf(1.f + fexp2f(x * -1.44269504f));
}
__device__ __forceinline__ float tanh_f(float x) {
    float e = fexp2f(x * 2.88539008f);
    return 1.f - 2.f * frcpf(e + 1.f);
}
__device__ __forceinline__ unsigned pk2(float a, float b) {
    __hip_bfloat162 r = __float22bfloat162_rn(make_float2(a, b));
    return *(unsigned*)&r;
}
__device__ __forceinline__ float b2f(ushort_t b) {
    return __uint_as_float(((unsigned)b) << 16);
}
__device__ __forceinline__ ushort_t f2b(float f) {
    unsigned u = __float_as_uint(f);
    u = (u + 0x7FFF + ((u >> 16) & 1)) >> 16;
    return (ushort_t)u;
}

// ---------------------------------------------------------------------------
// Convert emb / Wih / Whh / SW^T to bf16 (packed cvt).
// ---------------------------------------------------------------------------
#define EMB_N   6400000          // 50000*128
#define W_N     49152            // 384*128
#define SW_N    16384            // 128*128
#define CVT_N   (EMB_N + 2 * W_N + SW_N)

__global__ __launch_bounds__(256) void cvt_kernel(
    const float* __restrict__ emb, const float* __restrict__ wih,
    const float* __restrict__ whh, const float* __restrict__ sw,
    ushort_t* __restrict__ embb, ushort_t* __restrict__ wihb,
    ushort_t* __restrict__ whhb, ushort_t* __restrict__ swtb)
{
    int i = (blockIdx.x * 256 + threadIdx.x) * 4;
    if (i >= CVT_N) return;
    if (i < EMB_N) {
        float4 v = *(const float4*)(emb + i);
        uint2 o; o.x = pk2(v.x, v.y); o.y = pk2(v.z, v.w);
        *(uint2*)(embb + i) = o;
    } else if (i < EMB_N + W_N) {
        int j = i - EMB_N;
        float4 v = *(const float4*)(wih + j);
        uint2 o; o.x = pk2(v.x, v.y); o.y = pk2(v.z, v.w);
        *(uint2*)(wihb + j) = o;
    } else if (i < EMB_N + 2 * W_N) {
        int j = i - EMB_N - W_N;
        float4 v = *(const float4*)(whh + j);
        uint2 o; o.x = pk2(v.x, v.y); o.y = pk2(v.z, v.w);
        *(uint2*)(whhb + j) = o;
    } else {
        int j = i - EMB_N - 2 * W_N;
        int f = j >> 7, e0 = j & 127;
        uint2 o;
        o.x = pk2(sw[(e0 + 0) * 128 + f], sw[(e0 + 1) * 128 + f]);
        o.y = pk2(sw[(e0 + 2) * 128 + f], sw[(e0 + 3) * 128 + f]);
        *(uint2*)(swtb + j) = o;         // SWt[f][e]
    }
}

// ---------------------------------------------------------------------------
// FUSED leaf GRU + attention + sibling-max (r9 verified, 77us). Block = 512
// thr, 128 child rows = 1 parent x 32 batch x 4 siblings (k-major). GRU is
// barrier-free (h -> separate hnew LDS); one barrier; attn+max read hnew.
// h5 never touches HBM. LDS 74.8 KB -> 2 blocks/CU.
// ---------------------------------------------------------------------------
__global__ __launch_bounds__(512, 2) void leafattn_mfma(
    const int* __restrict__ tokens, const ushort_t* __restrict__ embb,
    const ushort_t* __restrict__ wihb,
    const float* __restrict__ bih, const float* __restrict__ bhh,
    const ushort_t* __restrict__ swt, const float* __restrict__ sb,
    const float* __restrict__ cw,
    ushort_t* __restrict__ h0out, ushort_t* __restrict__ pmaxs)
{
    __shared__ ushort_t xs[128 * 136];
    __shared__ ushort_t hnew[128 * 136];
    __shared__ float scp[8][128];
    __shared__ float sc[128];
    __shared__ float al[4][32];

    const int t = threadIdx.x;
    const int pn = blockIdx.x >> 3;          // parent node 0..255
    const int b0 = (blockIdx.x & 7) * 32;    // batch tile

    {
        int lr = t >> 2, c0 = (t & 3) * 32;
        int node = 4 * pn + (lr >> 5), b = b0 + (lr & 31);
        int tok = tokens[(341 + node) * 256 + b];
        const ushort_t* src = embb + (size_t)tok * 128 + c0;
        ushort_t* dst = &xs[lr * 136 + c0];
        #pragma unroll
        for (int i = 0; i < 4; ++i) *(s8*)(dst + 8 * i) = *(const s8*)(src + 8 * i);
    }

    const int lane = t & 63, w = t >> 6;
    const int quad = lane >> 4, l15 = lane & 15;
    const int gA = w * 16 + l15;
    const int g0 = w * 16 + quad * 4;

    s8 bwi[3][4];
    #pragma unroll
    for (int gm = 0; gm < 3; ++gm) {
        const ushort_t* wp = wihb + (size_t)(gm * 128 + gA) * 128 + quad * 8;
        #pragma unroll
        for (int s = 0; s < 4; ++s) bwi[gm][s] = *(const s8*)(wp + 32 * s);
    }
    float bR[4], bZ[4], biN[4], bhN[4];
    {
        float4 a = *(const float4*)(bih + g0);
        float4 b = *(const float4*)(bhh + g0);
        bR[0] = a.x + b.x; bR[1] = a.y + b.y; bR[2] = a.z + b.z; bR[3] = a.w + b.w;
        float4 c = *(const float4*)(bih + 128 + g0);
        float4 d = *(const float4*)(bhh + 128 + g0);
        bZ[0] = c.x + d.x; bZ[1] = c.y + d.y; bZ[2] = c.z + d.z; bZ[3] = c.w + d.w;
        float4 e = *(const float4*)(bih + 256 + g0);
        float4 f = *(const float4*)(bhh + 256 + g0);
        biN[0] = e.x; biN[1] = e.y; biN[2] = e.z; biN[3] = e.w;
        bhN[0] = f.x; bhN[1] = f.y; bhN[2] = f.z; bhN[3] = f.w;
    }

    __syncthreads();

    #pragma unroll 1
    for (int mt = 0; mt < 8; ++mt) {
        const int row = mt * 16 + l15;
        s8 ax[4];
        const ushort_t* ap = &xs[row * 136 + quad * 8];
        #pragma unroll
        for (int s = 0; s < 4; ++s) ax[s] = *(const s8*)(ap + 32 * s);

        f4 accR = (f4)0.f, accZ = (f4)0.f, accN = (f4)0.f;
        #pragma unroll
        for (int s = 0; s < 4; ++s) {
            accR = __builtin_amdgcn_mfma_f32_16x16x32_bf16(bwi[0][s], ax[s], accR, 0, 0, 0);
            accZ = __builtin_amdgcn_mfma_f32_16x16x32_bf16(bwi[1][s], ax[s], accZ, 0, 0, 0);
            accN = __builtin_amdgcn_mfma_f32_16x16x32_bf16(bwi[2][s], ax[s], accN, 0, 0, 0);
        }
        float hv[4];
        #pragma unroll
        for (int r = 0; r < 4; ++r) {
            float rr = sigf(accR[r] + bR[r]);
            float zz = sigf(accZ[r] + bZ[r]);
            float nn = tanh_f(accN[r] + biN[r] + rr * bhN[r]);
            hv[r] = nn - zz * nn;
        }
        uint2 ov; ov.x = pk2(hv[0], hv[1]); ov.y = pk2(hv[2], hv[3]);
        *(uint2*)&hnew[row * 136 + g0] = ov;
    }
    __syncthreads();

    s8 bsw[4];
    {
        const ushort_t* wp = swt + (size_t)gA * 128 + quad * 8;
        #pragma unroll
        for (int s = 0; s < 4; ++s) bsw[s] = *(const s8*)(wp + 32 * s);
    }
    float sb4[4], cw4[4];
    {
        float4 a = *(const float4*)(sb + g0);
        float4 b = *(const float4*)(cw + g0);
        sb4[0] = a.x; sb4[1] = a.y; sb4[2] = a.z; sb4[3] = a.w;
        cw4[0] = b.x; cw4[1] = b.y; cw4[2] = b.z; cw4[3] = b.w;
    }

    #pragma unroll 1
    for (int mt = 0; mt < 8; ++mt) {
        const int crow = mt * 16 + l15;
        s8 a[4];
        const ushort_t* ap = &hnew[crow * 136 + quad * 8];
        #pragma unroll
        for (int s = 0; s < 4; ++s) a[s] = *(const s8*)(ap + 32 * s);

        f4 acc = (f4)0.f;
        #pragma unroll
        for (int s = 0; s < 4; ++s)
            acc = __builtin_amdgcn_mfma_f32_16x16x32_bf16(bsw[s], a[s], acc, 0, 0, 0);

        float part = 0.f;
        #pragma unroll
        for (int r = 0; r < 4; ++r)
            part += tanh_f(acc[r] + sb4[r]) * cw4[r];
        part += __shfl_xor(part, 16);
        part += __shfl_xor(part, 32);
        if (quad == 0) scp[w][crow] = part;
    }
    __syncthreads();

    if (t < 128) {
        float s = 0.f;
        #pragma unroll
        for (int ww = 0; ww < 8; ++ww) s += scp[ww][t];
        sc[t] = tanh_f(s);
    }
    __syncthreads();

    if (t < 32) {
        float s0 = sc[t], s1 = sc[32 + t], s2 = sc[64 + t], s3 = sc[96 + t];
        float m = fmaxf(fmaxf(s0, s1), fmaxf(s2, s3));
        float e0 = fexp2f((s0 - m) * 1.44269504f), e1 = fexp2f((s1 - m) * 1.44269504f);
        float e2 = fexp2f((s2 - m) * 1.44269504f), e3 = fexp2f((s3 - m) * 1.44269504f);
        float inv = frcpf(e0 + e1 + e2 + e3);
        al[0][t] = e0 * inv; al[1][t] = e1 * inv; al[2][t] = e2 * inv; al[3][t] = e3 * inv;
    }
    __syncthreads();

    {
        int bl = t >> 4, e0 = (t & 15) * 8;
        float a0 = al[0][bl], a1 = al[1][bl], a2 = al[2][bl], a3 = al[3][bl];
        s8 c0v = *(const s8*)&hnew[(0 * 32 + bl) * 136 + e0];
        s8 c1v = *(const s8*)&hnew[(1 * 32 + bl) * 136 + e0];
        s8 c2v = *(const s8*)&hnew[(2 * 32 + bl) * 136 + e0];
        s8 c3v = *(const s8*)&hnew[(3 * 32 + bl) * 136 + e0];
        float o[8], m[8];
        #pragma unroll
        for (int j = 0; j < 8; ++j) {
            float x0 = b2f((ushort_t)c0v[j]), x1 = b2f((ushort_t)c1v[j]);
            float x2 = b2f((ushort_t)c2v[j]), x3 = b2f((ushort_t)c3v[j]);
            o[j] = a0 * x0 + a1 * x1 + a2 * x2 + a3 * x3;
            m[j] = fmaxf(fmaxf(x0, x1), fmaxf(x2, x3));
        }
        uint4 ovv, mvv;
        ovv.x = pk2(o[0], o[1]); ovv.y = pk2(o[2], o[3]);
        ovv.z = pk2(o[4], o[5]); ovv.w = pk2(o[6], o[7]);
        mvv.x = pk2(m[0], m[1]); mvv.y = pk2(m[2], m[3]);
        mvv.z = pk2(m[4], m[5]); mvv.w = pk2(m[6], m[7]);
        size_t ro = ((size_t)pn * 256 + b0 + bl) * 128 + e0;
        *(uint4*)(h0out + ro) = ovv;
        *(uint4*)(pmaxs + ro) = mvv;
    }
}

// ---------------------------------------------------------------------------
// GRU step with h0 (r11 structure) — used for L4 only.
// ---------------------------------------------------------------------------
__global__ __launch_bounds__(512, 2) void gru_mfma(
    const int* __restrict__ tokens, const ushort_t* __restrict__ embb,
    const ushort_t* __restrict__ wihb, const ushort_t* __restrict__ whhb,
    const float* __restrict__ bih, const float* __restrict__ bhh,
    const ushort_t* __restrict__ h0buf, ushort_t* __restrict__ hbuf,
    int lvl_start)
{
    __shared__ ushort_t xs[128 * 136];
    __shared__ ushort_t hs[128 * 136];

    const int t = threadIdx.x;
    const int base = blockIdx.x * 128;

    {
        int rl = t >> 2, c0 = (t & 3) * 32;
        int row = base + rl;
        int tok = tokens[(lvl_start + (row >> 8)) * 256 + (row & 255)];
        const ushort_t* src = embb + (size_t)tok * 128 + c0;
        ushort_t* dst = &xs[rl * 136 + c0];
        #pragma unroll
        for (int i = 0; i < 4; ++i) *(s8*)(dst + 8 * i) = *(const s8*)(src + 8 * i);
        const ushort_t* hsrc = h0buf + (size_t)row * 128 + c0;
        ushort_t* hdst = &hs[rl * 136 + c0];
        #pragma unroll
        for (int i = 0; i < 4; ++i) *(s8*)(hdst + 8 * i) = *(const s8*)(hsrc + 8 * i);
    }

    const int lane = t & 63, w = t >> 6;
    const int quad = lane >> 4, l15 = lane & 15;
    const int gA = w * 16 + l15;
    const int g0 = w * 16 + quad * 4;

    s8 bwi[3][4], bwh[3][4];
    #pragma unroll
    for (int gm = 0; gm < 3; ++gm) {
        const ushort_t* wp = wihb + (size_t)(gm * 128 + gA) * 128 + quad * 8;
        #pragma unroll
        for (int s = 0; s < 4; ++s) bwi[gm][s] = *(const s8*)(wp + 32 * s);
        const ushort_t* wp2 = whhb + (size_t)(gm * 128 + gA) * 128 + quad * 8;
        #pragma unroll
        for (int s = 0; s < 4; ++s) bwh[gm][s] = *(const s8*)(wp2 + 32 * s);
    }

    float bR[4], bZ[4], biN[4], bhN[4];
    {
        float4 a = *(const float4*)(bih + g0);
        float4 b = *(const float4*)(bhh + g0);
        bR[0] = a.x + b.x; bR[1] = a.y + b.y; bR[2] = a.z + b.z; bR[3] = a.w + b.w;
        float4 c = *(const float4*)(bih + 128 + g0);
        float4 d = *(const float4*)(bhh + 128 + g0);
        bZ[0] = c.x + d.x; bZ[1] = c.y + d.y; bZ[2] = c.z + d.z; bZ[3] = c.w + d.w;
        float4 e = *(const float4*)(bih + 256 + g0);
        float4 f = *(const float4*)(bhh + 256 + g0);
        biN[0] = e.x; biN[1] = e.y; biN[2] = e.z; biN[3] = e.w;
        bhN[0] = f.x; bhN[1] = f.y; bhN[2] = f.z; bhN[3] = f.w;
    }

    __syncthreads();

    #pragma unroll 1
    for (int mt = 0; mt < 8; ++mt) {
        const int row = mt * 16 + l15;
        s8 ax[4], ah[4];
        {
            const ushort_t* ap = &xs[row * 136 + quad * 8];
            #pragma unroll
            for (int s = 0; s < 4; ++s) ax[s] = *(const s8*)(ap + 32 * s);
            const ushort_t* hp = &hs[row * 136 + quad * 8];
            #pragma unroll
            for (int s = 0; s < 4; ++s) ah[s] = *(const s8*)(hp + 32 * s);
        }

        f4 accR = (f4)0.f, accZ = (f4)0.f, accN = (f4)0.f, accNh = (f4)0.f;
        #pragma unroll
        for (int s = 0; s < 4; ++s) {
            accR = __builtin_amdgcn_mfma_f32_16x16x32_bf16(bwi[0][s], ax[s], accR, 0, 0, 0);
            accZ = __builtin_amdgcn_mfma_f32_16x16x32_bf16(bwi[1][s], ax[s], accZ, 0, 0, 0);
            accN = __builtin_amdgcn_mfma_f32_16x16x32_bf16(bwi[2][s], ax[s], accN, 0, 0, 0);
        }
        #pragma unroll
        for (int s = 0; s < 4; ++s) {
            accR  = __builtin_amdgcn_mfma_f32_16x16x32_bf16(bwh[0][s], ah[s], accR, 0, 0, 0);
            accZ  = __builtin_amdgcn_mfma_f32_16x16x32_bf16(bwh[1][s], ah[s], accZ, 0, 0, 0);
            accNh = __builtin_amdgcn_mfma_f32_16x16x32_bf16(bwh[2][s], ah[s], accNh, 0, 0, 0);
        }

        float h0v[4];
        {
            short4 h04 = *(const short4*)&hs[row * 136 + g0];
            h0v[0] = b2f((ushort_t)h04.x); h0v[1] = b2f((ushort_t)h04.y);
            h0v[2] = b2f((ushort_t)h04.z); h0v[3] = b2f((ushort_t)h04.w);
        }
        float hv[4];
        #pragma unroll
        for (int r = 0; r < 4; ++r) {
            float rr = sigf(accR[r] + bR[r]);
            float zz = sigf(accZ[r] + bZ[r]);
            float nn = tanh_f(accN[r] + biN[r] + rr * (accNh[r] + bhN[r]));
            hv[r] = nn + zz * (h0v[r] - nn);
        }
        uint2 ov; ov.x = pk2(hv[0], hv[1]); ov.y = pk2(hv[2], hv[3]);
        *(uint2*)(hbuf + (size_t)(base + row) * 128 + g0) = ov;
    }
}

// ---------------------------------------------------------------------------
// Attention + sibling-max (r11 structure) — used for L4 only.
// ---------------------------------------------------------------------------
__global__ __launch_bounds__(512, 2) void attnmax_mfma(
    const ushort_t* __restrict__ hch, ushort_t* __restrict__ h0out,
    ushort_t* __restrict__ pmaxs,
    const ushort_t* __restrict__ swt, const float* __restrict__ sb,
    const float* __restrict__ cw)
{
    __shared__ ushort_t chs[128 * 136];
    __shared__ float scp[8][128];
    __shared__ float sc[128];
    __shared__ float al[4][32];

    const int t = threadIdx.x;
    const int pbase = blockIdx.x * 32;
    const int pnode = pbase >> 8;
    const int b0 = pbase & 255;

    {
        int lr = t >> 2, c0 = (t & 3) * 32;
        int k = lr >> 5, bl = lr & 31;
        const ushort_t* src = hch + ((size_t)(4 * pnode + k) * 256 + b0 + bl) * 128 + c0;
        ushort_t* dst = &chs[lr * 136 + c0];
        #pragma unroll
        for (int i = 0; i < 4; ++i) *(s8*)(dst + 8 * i) = *(const s8*)(src + 8 * i);
    }

    const int lane = t & 63, w = t >> 6;
    const int quad = lane >> 4, l15 = lane & 15;
    const int fA = w * 16 + l15;
    const int f0 = w * 16 + quad * 4;

    s8 bsw[4];
    {
        const ushort_t* wp = swt + (size_t)fA * 128 + quad * 8;
        #pragma unroll
        for (int s = 0; s < 4; ++s) bsw[s] = *(const s8*)(wp + 32 * s);
    }
    float sb4[4], cw4[4];
    {
        float4 a = *(const float4*)(sb + f0);
        float4 b = *(const float4*)(cw + f0);
        sb4[0] = a.x; sb4[1] = a.y; sb4[2] = a.z; sb4[3] = a.w;
        cw4[0] = b.x; cw4[1] = b.y; cw4[2] = b.z; cw4[3] = b.w;
    }
    __syncthreads();

    #pragma unroll 1
    for (int mt = 0; mt < 8; ++mt) {
        const int crow = mt * 16 + l15;
        s8 a[4];
        const ushort_t* ap = &chs[crow * 136 + quad * 8];
        #pragma unroll
        for (int s = 0; s < 4; ++s) a[s] = *(const s8*)(ap + 32 * s);

        f4 acc = (f4)0.f;
        #pragma unroll
        for (int s = 0; s < 4; ++s)
            acc = __builtin_amdgcn_mfma_f32_16x16x32_bf16(bsw[s], a[s], acc, 0, 0, 0);

        float part = 0.f;
        #pragma unroll
        for (int r = 0; r < 4; ++r)
            part += tanh_f(acc[r] + sb4[r]) * cw4[r];
        part += __shfl_xor(part, 16);
        part += __shfl_xor(part, 32);
        if (quad == 0) scp[w][crow] = part;
    }
    __syncthreads();

    if (t < 128) {
        float s = 0.f;
        #pragma unroll
        for (int ww = 0; ww < 8; ++ww) s += scp[ww][t];
        sc[t] = tanh_f(s);
    }
    __syncthreads();

    if (t < 32) {
        float s0 = sc[t], s1 = sc[32 + t], s2 = sc[64 + t], s3 = sc[96 + t];
        float m = fmaxf(fmaxf(s0, s1), fmaxf(s2, s3));
        float e0 = fexp2f((s0 - m) * 1.44269504f), e1 = fexp2f((s1 - m) * 1.44269504f);
        float e2 = fexp2f((s2 - m) * 1.44269504f), e3 = fexp2f((s3 - m) * 1.44269504f);
        float inv = frcpf(e0 + e1 + e2 + e3);
        al[0][t] = e0 * inv; al[1][t] = e1 * inv; al[2][t] = e2 * inv; al[3][t] = e3 * inv;
    }
    __syncthreads();

    {
        int bl = t >> 4, e0 = (t & 15) * 8;
        float a0 = al[0][bl], a1 = al[1][bl], a2 = al[2][bl], a3 = al[3][bl];
        s8 c0v = *(const s8*)&chs[(0 * 32 + bl) * 136 + e0];
        s8 c1v = *(const s8*)&chs[(1 * 32 + bl) * 136 + e0];
        s8 c2v = *(const s8*)&chs[(2 * 32 + bl) * 136 + e0];
        s8 c3v = *(const s8*)&chs[(3 * 32 + bl) * 136 + e0];
        float o[8], m[8];
        #pragma unroll
        for (int j = 0; j < 8; ++j) {
            float x0 = b2f((ushort_t)c0v[j]), x1 = b2f((ushort_t)c1v[j]);
            float x2 = b2f((ushort_t)c2v[j]), x3 = b2f((ushort_t)c3v[j]);
            o[j] = a0 * x0 + a1 * x1 + a2 * x2 + a3 * x3;
            m[j] = fmaxf(fmaxf(x0, x1), fmaxf(x2, x3));
        }
        uint4 ovv, mvv;
        ovv.x = pk2(o[0], o[1]); ovv.y = pk2(o[2], o[3]);
        ovv.z = pk2(o[4], o[5]); ovv.w = pk2(o[6], o[7]);
        mvv.x = pk2(m[0], m[1]); mvv.y = pk2(m[2], m[3]);
        mvv.z = pk2(m[4], m[5]); mvv.w = pk2(m[6], m[7]);
        size_t ro = (size_t)(pbase + bl) * 128 + e0;
        *(uint4*)(h0out + ro) = ovv;
        *(uint4*)(pmaxs + ro) = mvv;
    }
}

// ---------------------------------------------------------------------------
// TAIL kernel: levels L3(64n), L2(16n), L1(4n), root in ONE launch.
// Batch-partitioned (r12's verified batch-separability, without its fetch
// blowup): grid = 128 blocks x 2 batch columns; levels run inside the block
// with __syncthreads; h0 passes through LDS (hs). Row layout: lr = node*2 +
// b_local. Pad rows clamp the node index (exact dups); their h0 reads use the
// clamped row hr. Running max in registers -> one bf16 pmax slot (320).
// ---------------------------------------------------------------------------
__global__ __launch_bounds__(512, 1) void tail_kernel(
    const int* __restrict__ tokens, const ushort_t* __restrict__ embb,
    const ushort_t* __restrict__ wihb, const ushort_t* __restrict__ whhb,
    const float* __restrict__ bih, const float* __restrict__ bhh,
    const ushort_t* __restrict__ swt, const float* __restrict__ sb,
    const float* __restrict__ cw,
    const ushort_t* __restrict__ h0g,      // h0 for L3 (64 nodes, global)
    ushort_t* __restrict__ pmaxs)          // slot 320
{
    __shared__ ushort_t xs[128 * 136];
    __shared__ ushort_t hnew[128 * 136];
    __shared__ ushort_t hs[128 * 136];     // h0: staged (L3), attn-written after
    __shared__ float scp[8][128];
    __shared__ float sc[128];
    __shared__ float al[4][32];
    __shared__ float smax[4][128];

    const int t = threadIdx.x;
    const int bb = blockIdx.x * 2;         // batch base (2 batch cols/block)
    const int lane = t & 63, w = t >> 6;
    const int quad = lane >> 4, l15 = lane & 15;
    const int gA = w * 16 + l15;
    const int g0 = w * 16 + quad * 4;

    s8 bwi[3][4], bwh[3][4];
    #pragma unroll
    for (int gm = 0; gm < 3; ++gm) {
        const ushort_t* wp = wihb + (size_t)(gm * 128 + gA) * 128 + quad * 8;
        #pragma unroll
        for (int s = 0; s < 4; ++s) bwi[gm][s] = *(const s8*)(wp + 32 * s);
        const ushort_t* wp2 = whhb + (size_t)(gm * 128 + gA) * 128 + quad * 8;
        #pragma unroll
        for (int s = 0; s < 4; ++s) bwh[gm][s] = *(const s8*)(wp2 + 32 * s);
    }
    float bR[4], bZ[4], biN[4], bhN[4];
    {
        float4 a = *(const float4*)(bih + g0);
        float4 b = *(const float4*)(bhh + g0);
        bR[0] = a.x + b.x; bR[1] = a.y + b.y; bR[2] = a.z + b.z; bR[3] = a.w + b.w;
        float4 c = *(const float4*)(bih + 128 + g0);
        float4 d = *(const float4*)(bhh + 128 + g0);
        bZ[0] = c.x + d.x; bZ[1] = c.y + d.y; bZ[2] = c.z + d.z; bZ[3] = c.w + d.w;
        float4 e = *(const float4*)(bih + 256 + g0);
        float4 f = *(const float4*)(bhh + 256 + g0);
        biN[0] = e.x; biN[1] = e.y; biN[2] = e.z; biN[3] = e.w;
        bhN[0] = f.x; bhN[1] = f.y; bhN[2] = f.z; bhN[3] = f.w;
    }
    s8 bsw[4];
    {
        const ushort_t* wp = swt + (size_t)gA * 128 + quad * 8;
        #pragma unroll
        for (int s = 0; s < 4; ++s) bsw[s] = *(const s8*)(wp + 32 * s);
    }
    float sb4[4], cw4[4];
    {
        float4 a = *(const float4*)(sb + g0);
        float4 b = *(const float4*)(cw + g0);
        sb4[0] = a.x; sb4[1] = a.y; sb4[2] = a.z; sb4[3] = a.w;
        cw4[0] = b.x; cw4[1] = b.y; cw4[2] = b.z; cw4[3] = b.w;
    }

    float vmax = -INFINITY;

    const int nodesA[4] = {64, 16, 4, 1};
    const int tok0A[4]  = {21, 5, 1, 0};

    for (int L = 0; L < 4; ++L) {
        const int nodes = nodesA[L], tok0 = tok0A[L];
        const int vrows = nodes * 2;
        const int R = (vrows + 15) & ~15;      // 128, 32, 16, 16
        const int mts = R >> 4;

        // ---- stage x (+h0 from global for L3): 4 thr/row, 32 shorts ----
        {
            int lr = t >> 2, c0 = (t & 3) * 32;
            if (lr < R) {
                int n = min(lr >> 1, nodes - 1);   // clamp -> dup pad rows
                int b = bb + (lr & 1);
                int tok = tokens[(tok0 + n) * 256 + b];
                const ushort_t* src = embb + (size_t)tok * 128 + c0;
                ushort_t* dst = &xs[lr * 136 + c0];
                #pragma unroll
                for (int i = 0; i < 4; ++i) *(s8*)(dst + 8 * i) = *(const s8*)(src + 8 * i);
                if (L == 0) {
                    const ushort_t* hsrc = h0g + ((size_t)n * 256 + b) * 128 + c0;
                    ushort_t* hdst = &hs[lr * 136 + c0];
                    #pragma unroll
                    for (int i = 0; i < 4; ++i) *(s8*)(hdst + 8 * i) = *(const s8*)(hsrc + 8 * i);
                }
            }
        }
        __syncthreads();

        // ---- GRU: wave w owns gate-col group w; iterate mts ----
        for (int mt = 0; mt < mts; ++mt) {
            const int row = mt * 16 + l15;
            const int hr = min(row >> 1, nodes - 1) * 2 + (row & 1);  // clamped h0 row
            s8 ax[4], ah[4];
            {
                const ushort_t* ap = &xs[row * 136 + quad * 8];
                #pragma unroll
                for (int s = 0; s < 4; ++s) ax[s] = *(const s8*)(ap + 32 * s);
                const ushort_t* hp = &hs[hr * 136 + quad * 8];
                #pragma unroll
                for (int s = 0; s < 4; ++s) ah[s] = *(const s8*)(hp + 32 * s);
            }
            f4 accR = (f4)0.f, accZ = (f4)0.f, accN = (f4)0.f, accNh = (f4)0.f;
            #pragma unroll
            for (int s = 0; s < 4; ++s) {
                accR = __builtin_amdgcn_mfma_f32_16x16x32_bf16(bwi[0][s], ax[s], accR, 0, 0, 0);
                accZ = __builtin_amdgcn_mfma_f32_16x16x32_bf16(bwi[1][s], ax[s], accZ, 0, 0, 0);
                accN = __builtin_amdgcn_mfma_f32_16x16x32_bf16(bwi[2][s], ax[s], accN, 0, 0, 0);
            }
            #pragma unroll
            for (int s = 0; s < 4; ++s) {
                accR  = __builtin_amdgcn_mfma_f32_16x16x32_bf16(bwh[0][s], ah[s], accR, 0, 0, 0);
                accZ  = __builtin_amdgcn_mfma_f32_16x16x32_bf16(bwh[1][s], ah[s], accZ, 0, 0, 0);
                accNh = __builtin_amdgcn_mfma_f32_16x16x32_bf16(bwh[2][s], ah[s], accNh, 0, 0, 0);
            }
            float h0v[4];
            {
                short4 h04 = *(const short4*)&hs[hr * 136 + g0];
                h0v[0] = b2f((ushort_t)h04.x); h0v[1] = b2f((ushort_t)h04.y);
                h0v[2] = b2f((ushort_t)h04.z); h0v[3] = b2f((ushort_t)h04.w);
            }
            float hv[4];
            #pragma unroll
            for (int r = 0; r < 4; ++r) {
                float rr = sigf(accR[r] + bR[r]);
                float zz = sigf(accZ[r] + bZ[r]);
                float nn = tanh_f(accN[r] + biN[r] + rr * (accNh[r] + bhN[r]));
                hv[r] = nn + zz * (h0v[r] - nn);
            }
            uint2 ov; ov.x = pk2(hv[0], hv[1]); ov.y = pk2(hv[2], hv[3]);
            *(uint2*)&hnew[row * 136 + g0] = ov;
        }
        __syncthreads();

        // ---- running max. Rows >= R hold previous-level h (already maxed,
        // same batch pair, same parity mapping) -> re-max is a no-op. Pad
        // rows are exact dups. Thread: col = t&127, g = t>>7 (b_local=g&1,
        // half=g>>1): rows b_local + 2k, 32 rows.
        {
            int col = t & 127, g = t >> 7;
            int r = (g & 1) + (g >> 1) * 64;
            #pragma unroll 4
            for (int k = 0; k < 32; ++k, r += 2)
                vmax = fmaxf(vmax, b2f(hnew[r * 136 + col]));
        }

        if (L < 3) {
            // ---- attention: siblings of parent (pj,b) = rows (4pj+k)*2+b ----
            for (int mt = 0; mt < mts; ++mt) {
                const int crow = mt * 16 + l15;
                s8 a[4];
                const ushort_t* ap = &hnew[crow * 136 + quad * 8];
                #pragma unroll
                for (int s = 0; s < 4; ++s) a[s] = *(const s8*)(ap + 32 * s);
                f4 acc = (f4)0.f;
                #pragma unroll
                for (int s = 0; s < 4; ++s)
                    acc = __builtin_amdgcn_mfma_f32_16x16x32_bf16(bsw[s], a[s], acc, 0, 0, 0);
                float part = 0.f;
                #pragma unroll
                for (int r = 0; r < 4; ++r)
                    part += tanh_f(acc[r] + sb4[r]) * cw4[r];
                part += __shfl_xor(part, 16);
                part += __shfl_xor(part, 32);
                if (quad == 0) scp[w][crow] = part;
            }
            __syncthreads();
            if (t < R) {
                float s = 0.f;
                #pragma unroll
                for (int g = 0; g < 8; ++g) s += scp[g][t];
                sc[t] = tanh_f(s);
            }
            __syncthreads();
            const int P = (nodes >> 2) * 2;    // parent rows: 32, 8, 2
            if (t < P) {
                int pj = t >> 1, b_ = t & 1;
                float s0 = sc[(4 * pj + 0) * 2 + b_], s1 = sc[(4 * pj + 1) * 2 + b_];
                float s2 = sc[(4 * pj + 2) * 2 + b_], s3 = sc[(4 * pj + 3) * 2 + b_];
                float m = fmaxf(fmaxf(s0, s1), fmaxf(s2, s3));
                float e0 = fexp2f((s0 - m) * 1.44269504f);
                float e1 = fexp2f((s1 - m) * 1.44269504f);
                float e2 = fexp2f((s2 - m) * 1.44269504f);
                float e3 = fexp2f((s3 - m) * 1.44269504f);
                float inv = frcpf(e0 + e1 + e2 + e3);
                al[0][t] = e0 * inv; al[1][t] = e1 * inv;
                al[2][t] = e2 * inv; al[3][t] = e3 * inv;
            }
            __syncthreads();
            if (t < 16 * P) {
                int bl = t >> 4, e0 = (t & 15) * 8;
                int pj = bl >> 1, b_ = bl & 1;
                float a0 = al[0][bl], a1 = al[1][bl], a2 = al[2][bl], a3 = al[3][bl];
                s8 c0v = *(const s8*)&hnew[((4 * pj + 0) * 2 + b_) * 136 + e0];
                s8 c1v = *(const s8*)&hnew[((4 * pj + 1) * 2 + b_) * 136 + e0];
                s8 c2v = *(const s8*)&hnew[((4 * pj + 2) * 2 + b_) * 136 + e0];
                s8 c3v = *(const s8*)&hnew[((4 * pj + 3) * 2 + b_) * 136 + e0];
                float o[8];
                #pragma unroll
                for (int j = 0; j < 8; ++j) {
                    o[j] = a0 * b2f((ushort_t)c0v[j]) + a1 * b2f((ushort_t)c1v[j])
                         + a2 * b2f((ushort_t)c2v[j]) + a3 * b2f((ushort_t)c3v[j]);
                }
                uint4 ovv;
                ovv.x = pk2(o[0], o[1]); ovv.y = pk2(o[2], o[3]);
                ovv.z = pk2(o[4], o[5]); ovv.w = pk2(o[6], o[7]);
                *(uint4*)&hs[bl * 136 + e0] = ovv;   // parent h0 -> hs row bl
            }
            __syncthreads();
        }
    }

    // ---- write pmax slot 320 rows bb, bb+1 ----
    smax[t >> 7][t & 127] = vmax;
    __syncthreads();
    if (t < 256) {
        int b_ = t >> 7, col = t & 127;
        float v = fmaxf(smax[b_][col], smax[b_ + 2][col]);
        pmaxs[(size_t)(bb + b_) * 128 + col] = f2b(v);
    }
}

// ---------------------------------------------------------------------------
// Two-stage final max over 321 bf16 slots (L5: 0..255 | L4: 256..319 | tail: 320).
// ---------------------------------------------------------------------------
#define N_SLOTS 321
__global__ __launch_bounds__(256) void max_stage1(
    const ushort_t* __restrict__ pmax, float* __restrict__ pm2)
{
    int e0 = (blockIdx.x * 256 + threadIdx.x) * 8;
    int y = blockIdx.y;
    int s0 = y * 41, s1 = min(N_SLOTS, s0 + 41);
    float v[8];
    #pragma unroll
    for (int j = 0; j < 8; ++j) v[j] = -INFINITY;
    for (int s = s0; s < s1; ++s) {
        s8 c = *(const s8*)(pmax + (size_t)s * 32768 + e0);
        #pragma unroll
        for (int j = 0; j < 8; ++j) v[j] = fmaxf(v[j], b2f((ushort_t)c[j]));
    }
    float* p = pm2 + (size_t)y * 32768 + e0;
    #pragma unroll
    for (int j = 0; j < 8; ++j) p[j] = v[j];
}

__global__ __launch_bounds__(256) void max_stage2(
    const float* __restrict__ pm2, float* __restrict__ out)
{
    int e0 = (blockIdx.x * 256 + threadIdx.x) * 8;
    float v[8];
    {
        float4 a = *(const float4*)(pm2 + e0);
        float4 b = *(const float4*)(pm2 + e0 + 4);
        v[0] = a.x; v[1] = a.y; v[2] = a.z; v[3] = a.w;
        v[4] = b.x; v[5] = b.y; v[6] = b.z; v[7] = b.w;
    }
    #pragma unroll
    for (int y = 1; y < 8; ++y) {
        float4 a = *(const float4*)(pm2 + (size_t)y * 32768 + e0);
        float4 b = *(const float4*)(pm2 + (size_t)y * 32768 + e0 + 4);
        v[0] = fmaxf(v[0], a.x); v[1] = fmaxf(v[1], a.y);
        v[2] = fmaxf(v[2], a.z); v[3] = fmaxf(v[3], a.w);
        v[4] = fmaxf(v[4], b.x); v[5] = fmaxf(v[5], b.y);
        v[6] = fmaxf(v[6], b.z); v[7] = fmaxf(v[7], b.w);
    }
    *(float4*)(out + e0)     = make_float4(v[0], v[1], v[2], v[3]);
    *(float4*)(out + e0 + 4) = make_float4(v[4], v[5], v[6], v[7]);
}

extern "C" void kernel_launch(void* const* d_in, const int* in_sizes, int n_in,
                              void* d_out, int out_size, void* d_ws, size_t ws_size,
                              hipStream_t stream)
{
    const int*   tokens = (const int*)d_in[0];
    const float* emb    = (const float*)d_in[1];
    const float* Wih    = (const float*)d_in[2];
    const float* Whh    = (const float*)d_in[3];
    const float* bih    = (const float*)d_in[4];
    const float* bhh    = (const float*)d_in[5];
    const float* SW     = (const float*)d_in[6];
    const float* sb     = (const float*)d_in[7];
    const float* cw     = (const float*)d_in[8];
    float* out = (float*)d_out;

    // ws layout
    ushort_t* embb = (ushort_t*)d_ws;                        // 12.8 MB
    ushort_t* wihb = embb + (size_t)EMB_N;
    ushort_t* whhb = wihb + W_N;
    ushort_t* swtb = whhb + W_N;
    ushort_t* h4   = swtb + SW_N;                            // 256n: 16.8 MB
    ushort_t* h0_4 = h4 + (size_t)256 * 32768;               // 256n
    ushort_t* h0_3 = h0_4 + (size_t)256 * 32768;             // 64n
    ushort_t* pmax = h0_3 + (size_t)64 * 32768;              // 321 slots: 21 MB
    float*    pm2  = (float*)(pmax + (size_t)N_SLOTS * 32768);

    cvt_kernel<<<(CVT_N / 4 + 255) / 256, 256, 0, stream>>>(
        emb, Wih, Whh, SW, embb, wihb, whhb, swtb);

    // L5 fused: leaf GRU + attn + sibling max -> h0_4 + pmax[0..255]
    leafattn_mfma<<<2048, 512, 0, stream>>>(
        tokens, embb, wihb, bih, bhh, swtb, sb, cw, h0_4, pmax);

    // L4 split (fusing measured worse): GRU then attn+max
    gru_mfma<<<512, 512, 0, stream>>>(
        tokens, embb, wihb, whhb, bih, bhh, h0_4, h4, 85);
    attnmax_mfma<<<512, 512, 0, stream>>>(h4, h0_3, pmax + (size_t)256 * 32768,
                                          swtb, sb, cw);

    // L3+L2+L1+root in one batch-partitioned kernel -> pmax[320]
    tail_kernel<<<128, 512, 0, stream>>>(
        tokens, embb, wihb, whhb, bih, bhh, swtb, sb, cw,
        h0_3, pmax + (size_t)320 * 32768);

    max_stage1<<<dim3(16, 8), 256, 0, stream>>>(pmax, pm2);
    max_stage2<<<16, 256, 0, stream>>>(pm2, out);
}

// Round 14
// 232.008 us; speedup vs baseline: 1.5851x; 1.0485x over previous
//
#include <hip/hip_runtime.h>
#include <hip/hip_bf16.h>
#include <math.h>

typedef short s8 __attribute__((ext_vector_type(8)));   // 8 bf16 in 4 VGPRs
typedef float f4 __attribute__((ext_vector_type(4)));   // MFMA 16x16 acc
typedef unsigned short ushort_t;

__device__ __forceinline__ float fexp2f(float x) { return __builtin_amdgcn_exp2f(x); }
__device__ __forceinline__ float frcpf(float x)  { return __builtin_amdgcn_rcpf(x); }
__device__ __forceinline__ float sigf(float x) {
    return frcpf(1.f + fexp2f(x * -1.44269504f));
}
__device__ __forceinline__ float tanh_f(float x) {
    float e = fexp2f(x * 2.88539008f);
    return 1.f - 2.f * frcpf(e + 1.f);
}
__device__ __forceinline__ unsigned pk2(float a, float b) {
    __hip_bfloat162 r = __float22bfloat162_rn(make_float2(a, b));
    return *(unsigned*)&r;
}
__device__ __forceinline__ float b2f(ushort_t b) {
    return __uint_as_float(((unsigned)b) << 16);
}
__device__ __forceinline__ ushort_t f2b(float f) {
    unsigned u = __float_as_uint(f);
    u = (u + 0x7FFF + ((u >> 16) & 1)) >> 16;
    return (ushort_t)u;
}

// ---------------------------------------------------------------------------
// Convert emb / Wih / Whh / SW^T to bf16 (packed cvt).
// ---------------------------------------------------------------------------
#define EMB_N   6400000          // 50000*128
#define W_N     49152            // 384*128
#define SW_N    16384            // 128*128
#define CVT_N   (EMB_N + 2 * W_N + SW_N)

__global__ __launch_bounds__(256) void cvt_kernel(
    const float* __restrict__ emb, const float* __restrict__ wih,
    const float* __restrict__ whh, const float* __restrict__ sw,
    ushort_t* __restrict__ embb, ushort_t* __restrict__ wihb,
    ushort_t* __restrict__ whhb, ushort_t* __restrict__ swtb)
{
    int i = (blockIdx.x * 256 + threadIdx.x) * 4;
    if (i >= CVT_N) return;
    if (i < EMB_N) {
        float4 v = *(const float4*)(emb + i);
        uint2 o; o.x = pk2(v.x, v.y); o.y = pk2(v.z, v.w);
        *(uint2*)(embb + i) = o;
    } else if (i < EMB_N + W_N) {
        int j = i - EMB_N;
        float4 v = *(const float4*)(wih + j);
        uint2 o; o.x = pk2(v.x, v.y); o.y = pk2(v.z, v.w);
        *(uint2*)(wihb + j) = o;
    } else if (i < EMB_N + 2 * W_N) {
        int j = i - EMB_N - W_N;
        float4 v = *(const float4*)(whh + j);
        uint2 o; o.x = pk2(v.x, v.y); o.y = pk2(v.z, v.w);
        *(uint2*)(whhb + j) = o;
    } else {
        int j = i - EMB_N - 2 * W_N;
        int f = j >> 7, e0 = j & 127;
        uint2 o;
        o.x = pk2(sw[(e0 + 0) * 128 + f], sw[(e0 + 1) * 128 + f]);
        o.y = pk2(sw[(e0 + 2) * 128 + f], sw[(e0 + 3) * 128 + f]);
        *(uint2*)(swtb + j) = o;         // SWt[f][e]
    }
}

// ---------------------------------------------------------------------------
// FUSED leaf GRU + attention + sibling-max (r9 verified). Block = 512 thr,
// 128 child rows = 1 parent x 32 batch x 4 siblings (k-major). GRU is
// barrier-free (h -> separate hnew LDS); one barrier; attn+max read hnew.
// h5 never touches HBM. LDS 74.8 KB -> 2 blocks/CU.
// ---------------------------------------------------------------------------
__global__ __launch_bounds__(512, 2) void leafattn_mfma(
    const int* __restrict__ tokens, const ushort_t* __restrict__ embb,
    const ushort_t* __restrict__ wihb,
    const float* __restrict__ bih, const float* __restrict__ bhh,
    const ushort_t* __restrict__ swt, const float* __restrict__ sb,
    const float* __restrict__ cw,
    ushort_t* __restrict__ h0out, ushort_t* __restrict__ pmaxs)
{
    __shared__ ushort_t xs[128 * 136];
    __shared__ ushort_t hnew[128 * 136];
    __shared__ float scp[8][128];
    __shared__ float sc[128];
    __shared__ float al[4][32];

    const int t = threadIdx.x;
    const int pn = blockIdx.x >> 3;          // parent node 0..255
    const int b0 = (blockIdx.x & 7) * 32;    // batch tile

    {
        int lr = t >> 2, c0 = (t & 3) * 32;
        int node = 4 * pn + (lr >> 5), b = b0 + (lr & 31);
        int tok = tokens[(341 + node) * 256 + b];
        const ushort_t* src = embb + (size_t)tok * 128 + c0;
        ushort_t* dst = &xs[lr * 136 + c0];
        #pragma unroll
        for (int i = 0; i < 4; ++i) *(s8*)(dst + 8 * i) = *(const s8*)(src + 8 * i);
    }

    const int lane = t & 63, w = t >> 6;
    const int quad = lane >> 4, l15 = lane & 15;
    const int gA = w * 16 + l15;
    const int g0 = w * 16 + quad * 4;

    s8 bwi[3][4];
    #pragma unroll
    for (int gm = 0; gm < 3; ++gm) {
        const ushort_t* wp = wihb + (size_t)(gm * 128 + gA) * 128 + quad * 8;
        #pragma unroll
        for (int s = 0; s < 4; ++s) bwi[gm][s] = *(const s8*)(wp + 32 * s);
    }
    float bR[4], bZ[4], biN[4], bhN[4];
    {
        float4 a = *(const float4*)(bih + g0);
        float4 b = *(const float4*)(bhh + g0);
        bR[0] = a.x + b.x; bR[1] = a.y + b.y; bR[2] = a.z + b.z; bR[3] = a.w + b.w;
        float4 c = *(const float4*)(bih + 128 + g0);
        float4 d = *(const float4*)(bhh + 128 + g0);
        bZ[0] = c.x + d.x; bZ[1] = c.y + d.y; bZ[2] = c.z + d.z; bZ[3] = c.w + d.w;
        float4 e = *(const float4*)(bih + 256 + g0);
        float4 f = *(const float4*)(bhh + 256 + g0);
        biN[0] = e.x; biN[1] = e.y; biN[2] = e.z; biN[3] = e.w;
        bhN[0] = f.x; bhN[1] = f.y; bhN[2] = f.z; bhN[3] = f.w;
    }

    __syncthreads();

    #pragma unroll 1
    for (int mt = 0; mt < 8; ++mt) {
        const int row = mt * 16 + l15;
        s8 ax[4];
        const ushort_t* ap = &xs[row * 136 + quad * 8];
        #pragma unroll
        for (int s = 0; s < 4; ++s) ax[s] = *(const s8*)(ap + 32 * s);

        f4 accR = (f4)0.f, accZ = (f4)0.f, accN = (f4)0.f;
        #pragma unroll
        for (int s = 0; s < 4; ++s) {
            accR = __builtin_amdgcn_mfma_f32_16x16x32_bf16(bwi[0][s], ax[s], accR, 0, 0, 0);
            accZ = __builtin_amdgcn_mfma_f32_16x16x32_bf16(bwi[1][s], ax[s], accZ, 0, 0, 0);
            accN = __builtin_amdgcn_mfma_f32_16x16x32_bf16(bwi[2][s], ax[s], accN, 0, 0, 0);
        }
        float hv[4];
        #pragma unroll
        for (int r = 0; r < 4; ++r) {
            float rr = sigf(accR[r] + bR[r]);
            float zz = sigf(accZ[r] + bZ[r]);
            float nn = tanh_f(accN[r] + biN[r] + rr * bhN[r]);
            hv[r] = nn - zz * nn;
        }
        uint2 ov; ov.x = pk2(hv[0], hv[1]); ov.y = pk2(hv[2], hv[3]);
        *(uint2*)&hnew[row * 136 + g0] = ov;
    }
    __syncthreads();

    s8 bsw[4];
    {
        const ushort_t* wp = swt + (size_t)gA * 128 + quad * 8;
        #pragma unroll
        for (int s = 0; s < 4; ++s) bsw[s] = *(const s8*)(wp + 32 * s);
    }
    float sb4[4], cw4[4];
    {
        float4 a = *(const float4*)(sb + g0);
        float4 b = *(const float4*)(cw + g0);
        sb4[0] = a.x; sb4[1] = a.y; sb4[2] = a.z; sb4[3] = a.w;
        cw4[0] = b.x; cw4[1] = b.y; cw4[2] = b.z; cw4[3] = b.w;
    }

    #pragma unroll 1
    for (int mt = 0; mt < 8; ++mt) {
        const int crow = mt * 16 + l15;
        s8 a[4];
        const ushort_t* ap = &hnew[crow * 136 + quad * 8];
        #pragma unroll
        for (int s = 0; s < 4; ++s) a[s] = *(const s8*)(ap + 32 * s);

        f4 acc = (f4)0.f;
        #pragma unroll
        for (int s = 0; s < 4; ++s)
            acc = __builtin_amdgcn_mfma_f32_16x16x32_bf16(bsw[s], a[s], acc, 0, 0, 0);

        float part = 0.f;
        #pragma unroll
        for (int r = 0; r < 4; ++r)
            part += tanh_f(acc[r] + sb4[r]) * cw4[r];
        part += __shfl_xor(part, 16);
        part += __shfl_xor(part, 32);
        if (quad == 0) scp[w][crow] = part;
    }
    __syncthreads();

    if (t < 128) {
        float s = 0.f;
        #pragma unroll
        for (int ww = 0; ww < 8; ++ww) s += scp[ww][t];
        sc[t] = tanh_f(s);
    }
    __syncthreads();

    if (t < 32) {
        float s0 = sc[t], s1 = sc[32 + t], s2 = sc[64 + t], s3 = sc[96 + t];
        float m = fmaxf(fmaxf(s0, s1), fmaxf(s2, s3));
        float e0 = fexp2f((s0 - m) * 1.44269504f), e1 = fexp2f((s1 - m) * 1.44269504f);
        float e2 = fexp2f((s2 - m) * 1.44269504f), e3 = fexp2f((s3 - m) * 1.44269504f);
        float inv = frcpf(e0 + e1 + e2 + e3);
        al[0][t] = e0 * inv; al[1][t] = e1 * inv; al[2][t] = e2 * inv; al[3][t] = e3 * inv;
    }
    __syncthreads();

    {
        int bl = t >> 4, e0 = (t & 15) * 8;
        float a0 = al[0][bl], a1 = al[1][bl], a2 = al[2][bl], a3 = al[3][bl];
        s8 c0v = *(const s8*)&hnew[(0 * 32 + bl) * 136 + e0];
        s8 c1v = *(const s8*)&hnew[(1 * 32 + bl) * 136 + e0];
        s8 c2v = *(const s8*)&hnew[(2 * 32 + bl) * 136 + e0];
        s8 c3v = *(const s8*)&hnew[(3 * 32 + bl) * 136 + e0];
        float o[8], m[8];
        #pragma unroll
        for (int j = 0; j < 8; ++j) {
            float x0 = b2f((ushort_t)c0v[j]), x1 = b2f((ushort_t)c1v[j]);
            float x2 = b2f((ushort_t)c2v[j]), x3 = b2f((ushort_t)c3v[j]);
            o[j] = a0 * x0 + a1 * x1 + a2 * x2 + a3 * x3;
            m[j] = fmaxf(fmaxf(x0, x1), fmaxf(x2, x3));
        }
        uint4 ovv, mvv;
        ovv.x = pk2(o[0], o[1]); ovv.y = pk2(o[2], o[3]);
        ovv.z = pk2(o[4], o[5]); ovv.w = pk2(o[6], o[7]);
        mvv.x = pk2(m[0], m[1]); mvv.y = pk2(m[2], m[3]);
        mvv.z = pk2(m[4], m[5]); mvv.w = pk2(m[6], m[7]);
        size_t ro = ((size_t)pn * 256 + b0 + bl) * 128 + e0;
        *(uint4*)(h0out + ro) = ovv;
        *(uint4*)(pmaxs + ro) = mvv;
    }
}

// ---------------------------------------------------------------------------
// GRU step with h0 (r11 structure) — used for L4 only.
// ---------------------------------------------------------------------------
__global__ __launch_bounds__(512, 2) void gru_mfma(
    const int* __restrict__ tokens, const ushort_t* __restrict__ embb,
    const ushort_t* __restrict__ wihb, const ushort_t* __restrict__ whhb,
    const float* __restrict__ bih, const float* __restrict__ bhh,
    const ushort_t* __restrict__ h0buf, ushort_t* __restrict__ hbuf,
    int lvl_start)
{
    __shared__ ushort_t xs[128 * 136];
    __shared__ ushort_t hs[128 * 136];

    const int t = threadIdx.x;
    const int base = blockIdx.x * 128;

    {
        int rl = t >> 2, c0 = (t & 3) * 32;
        int row = base + rl;
        int tok = tokens[(lvl_start + (row >> 8)) * 256 + (row & 255)];
        const ushort_t* src = embb + (size_t)tok * 128 + c0;
        ushort_t* dst = &xs[rl * 136 + c0];
        #pragma unroll
        for (int i = 0; i < 4; ++i) *(s8*)(dst + 8 * i) = *(const s8*)(src + 8 * i);
        const ushort_t* hsrc = h0buf + (size_t)row * 128 + c0;
        ushort_t* hdst = &hs[rl * 136 + c0];
        #pragma unroll
        for (int i = 0; i < 4; ++i) *(s8*)(hdst + 8 * i) = *(const s8*)(hsrc + 8 * i);
    }

    const int lane = t & 63, w = t >> 6;
    const int quad = lane >> 4, l15 = lane & 15;
    const int gA = w * 16 + l15;
    const int g0 = w * 16 + quad * 4;

    s8 bwi[3][4], bwh[3][4];
    #pragma unroll
    for (int gm = 0; gm < 3; ++gm) {
        const ushort_t* wp = wihb + (size_t)(gm * 128 + gA) * 128 + quad * 8;
        #pragma unroll
        for (int s = 0; s < 4; ++s) bwi[gm][s] = *(const s8*)(wp + 32 * s);
        const ushort_t* wp2 = whhb + (size_t)(gm * 128 + gA) * 128 + quad * 8;
        #pragma unroll
        for (int s = 0; s < 4; ++s) bwh[gm][s] = *(const s8*)(wp2 + 32 * s);
    }

    float bR[4], bZ[4], biN[4], bhN[4];
    {
        float4 a = *(const float4*)(bih + g0);
        float4 b = *(const float4*)(bhh + g0);
        bR[0] = a.x + b.x; bR[1] = a.y + b.y; bR[2] = a.z + b.z; bR[3] = a.w + b.w;
        float4 c = *(const float4*)(bih + 128 + g0);
        float4 d = *(const float4*)(bhh + 128 + g0);
        bZ[0] = c.x + d.x; bZ[1] = c.y + d.y; bZ[2] = c.z + d.z; bZ[3] = c.w + d.w;
        float4 e = *(const float4*)(bih + 256 + g0);
        float4 f = *(const float4*)(bhh + 256 + g0);
        biN[0] = e.x; biN[1] = e.y; biN[2] = e.z; biN[3] = e.w;
        bhN[0] = f.x; bhN[1] = f.y; bhN[2] = f.z; bhN[3] = f.w;
    }

    __syncthreads();

    #pragma unroll 1
    for (int mt = 0; mt < 8; ++mt) {
        const int row = mt * 16 + l15;
        s8 ax[4], ah[4];
        {
            const ushort_t* ap = &xs[row * 136 + quad * 8];
            #pragma unroll
            for (int s = 0; s < 4; ++s) ax[s] = *(const s8*)(ap + 32 * s);
            const ushort_t* hp = &hs[row * 136 + quad * 8];
            #pragma unroll
            for (int s = 0; s < 4; ++s) ah[s] = *(const s8*)(hp + 32 * s);
        }

        f4 accR = (f4)0.f, accZ = (f4)0.f, accN = (f4)0.f, accNh = (f4)0.f;
        #pragma unroll
        for (int s = 0; s < 4; ++s) {
            accR = __builtin_amdgcn_mfma_f32_16x16x32_bf16(bwi[0][s], ax[s], accR, 0, 0, 0);
            accZ = __builtin_amdgcn_mfma_f32_16x16x32_bf16(bwi[1][s], ax[s], accZ, 0, 0, 0);
            accN = __builtin_amdgcn_mfma_f32_16x16x32_bf16(bwi[2][s], ax[s], accN, 0, 0, 0);
        }
        #pragma unroll
        for (int s = 0; s < 4; ++s) {
            accR  = __builtin_amdgcn_mfma_f32_16x16x32_bf16(bwh[0][s], ah[s], accR, 0, 0, 0);
            accZ  = __builtin_amdgcn_mfma_f32_16x16x32_bf16(bwh[1][s], ah[s], accZ, 0, 0, 0);
            accNh = __builtin_amdgcn_mfma_f32_16x16x32_bf16(bwh[2][s], ah[s], accNh, 0, 0, 0);
        }

        float h0v[4];
        {
            short4 h04 = *(const short4*)&hs[row * 136 + g0];
            h0v[0] = b2f((ushort_t)h04.x); h0v[1] = b2f((ushort_t)h04.y);
            h0v[2] = b2f((ushort_t)h04.z); h0v[3] = b2f((ushort_t)h04.w);
        }
        float hv[4];
        #pragma unroll
        for (int r = 0; r < 4; ++r) {
            float rr = sigf(accR[r] + bR[r]);
            float zz = sigf(accZ[r] + bZ[r]);
            float nn = tanh_f(accN[r] + biN[r] + rr * (accNh[r] + bhN[r]));
            hv[r] = nn + zz * (h0v[r] - nn);
        }
        uint2 ov; ov.x = pk2(hv[0], hv[1]); ov.y = pk2(hv[2], hv[3]);
        *(uint2*)(hbuf + (size_t)(base + row) * 128 + g0) = ov;
    }
}

// ---------------------------------------------------------------------------
// Attention + sibling-max (r11 structure) — used for L4 only.
// ---------------------------------------------------------------------------
__global__ __launch_bounds__(512, 2) void attnmax_mfma(
    const ushort_t* __restrict__ hch, ushort_t* __restrict__ h0out,
    ushort_t* __restrict__ pmaxs,
    const ushort_t* __restrict__ swt, const float* __restrict__ sb,
    const float* __restrict__ cw)
{
    __shared__ ushort_t chs[128 * 136];
    __shared__ float scp[8][128];
    __shared__ float sc[128];
    __shared__ float al[4][32];

    const int t = threadIdx.x;
    const int pbase = blockIdx.x * 32;
    const int pnode = pbase >> 8;
    const int b0 = pbase & 255;

    {
        int lr = t >> 2, c0 = (t & 3) * 32;
        int k = lr >> 5, bl = lr & 31;
        const ushort_t* src = hch + ((size_t)(4 * pnode + k) * 256 + b0 + bl) * 128 + c0;
        ushort_t* dst = &chs[lr * 136 + c0];
        #pragma unroll
        for (int i = 0; i < 4; ++i) *(s8*)(dst + 8 * i) = *(const s8*)(src + 8 * i);
    }

    const int lane = t & 63, w = t >> 6;
    const int quad = lane >> 4, l15 = lane & 15;
    const int fA = w * 16 + l15;
    const int f0 = w * 16 + quad * 4;

    s8 bsw[4];
    {
        const ushort_t* wp = swt + (size_t)fA * 128 + quad * 8;
        #pragma unroll
        for (int s = 0; s < 4; ++s) bsw[s] = *(const s8*)(wp + 32 * s);
    }
    float sb4[4], cw4[4];
    {
        float4 a = *(const float4*)(sb + f0);
        float4 b = *(const float4*)(cw + f0);
        sb4[0] = a.x; sb4[1] = a.y; sb4[2] = a.z; sb4[3] = a.w;
        cw4[0] = b.x; cw4[1] = b.y; cw4[2] = b.z; cw4[3] = b.w;
    }
    __syncthreads();

    #pragma unroll 1
    for (int mt = 0; mt < 8; ++mt) {
        const int crow = mt * 16 + l15;
        s8 a[4];
        const ushort_t* ap = &chs[crow * 136 + quad * 8];
        #pragma unroll
        for (int s = 0; s < 4; ++s) a[s] = *(const s8*)(ap + 32 * s);

        f4 acc = (f4)0.f;
        #pragma unroll
        for (int s = 0; s < 4; ++s)
            acc = __builtin_amdgcn_mfma_f32_16x16x32_bf16(bsw[s], a[s], acc, 0, 0, 0);

        float part = 0.f;
        #pragma unroll
        for (int r = 0; r < 4; ++r)
            part += tanh_f(acc[r] + sb4[r]) * cw4[r];
        part += __shfl_xor(part, 16);
        part += __shfl_xor(part, 32);
        if (quad == 0) scp[w][crow] = part;
    }
    __syncthreads();

    if (t < 128) {
        float s = 0.f;
        #pragma unroll
        for (int ww = 0; ww < 8; ++ww) s += scp[ww][t];
        sc[t] = tanh_f(s);
    }
    __syncthreads();

    if (t < 32) {
        float s0 = sc[t], s1 = sc[32 + t], s2 = sc[64 + t], s3 = sc[96 + t];
        float m = fmaxf(fmaxf(s0, s1), fmaxf(s2, s3));
        float e0 = fexp2f((s0 - m) * 1.44269504f), e1 = fexp2f((s1 - m) * 1.44269504f);
        float e2 = fexp2f((s2 - m) * 1.44269504f), e3 = fexp2f((s3 - m) * 1.44269504f);
        float inv = frcpf(e0 + e1 + e2 + e3);
        al[0][t] = e0 * inv; al[1][t] = e1 * inv; al[2][t] = e2 * inv; al[3][t] = e3 * inv;
    }
    __syncthreads();

    {
        int bl = t >> 4, e0 = (t & 15) * 8;
        float a0 = al[0][bl], a1 = al[1][bl], a2 = al[2][bl], a3 = al[3][bl];
        s8 c0v = *(const s8*)&chs[(0 * 32 + bl) * 136 + e0];
        s8 c1v = *(const s8*)&chs[(1 * 32 + bl) * 136 + e0];
        s8 c2v = *(const s8*)&chs[(2 * 32 + bl) * 136 + e0];
        s8 c3v = *(const s8*)&chs[(3 * 32 + bl) * 136 + e0];
        float o[8], m[8];
        #pragma unroll
        for (int j = 0; j < 8; ++j) {
            float x0 = b2f((ushort_t)c0v[j]), x1 = b2f((ushort_t)c1v[j]);
            float x2 = b2f((ushort_t)c2v[j]), x3 = b2f((ushort_t)c3v[j]);
            o[j] = a0 * x0 + a1 * x1 + a2 * x2 + a3 * x3;
            m[j] = fmaxf(fmaxf(x0, x1), fmaxf(x2, x3));
        }
        uint4 ovv, mvv;
        ovv.x = pk2(o[0], o[1]); ovv.y = pk2(o[2], o[3]);
        ovv.z = pk2(o[4], o[5]); ovv.w = pk2(o[6], o[7]);
        mvv.x = pk2(m[0], m[1]); mvv.y = pk2(m[2], m[3]);
        mvv.z = pk2(m[4], m[5]); mvv.w = pk2(m[6], m[7]);
        size_t ro = (size_t)(pbase + bl) * 128 + e0;
        *(uint4*)(h0out + ro) = ovv;
        *(uint4*)(pmaxs + ro) = mvv;
    }
}

// ---------------------------------------------------------------------------
// TAIL kernel: levels L3(64n), L2(16n), L1(4n), root + FINAL MAX in ONE
// launch. Batch-partitioned: grid = 128 blocks x 2 batch columns; levels run
// inside the block with __syncthreads; h0 passes through LDS. After its own
// levels, each block reduces the 320 global pmax slots (L5+L4, written by
// earlier stream-ordered kernels) for its 2 batch rows and writes fp32 out.
// ---------------------------------------------------------------------------
__global__ __launch_bounds__(512, 1) void tail_kernel(
    const int* __restrict__ tokens, const ushort_t* __restrict__ embb,
    const ushort_t* __restrict__ wihb, const ushort_t* __restrict__ whhb,
    const float* __restrict__ bih, const float* __restrict__ bhh,
    const ushort_t* __restrict__ swt, const float* __restrict__ sb,
    const float* __restrict__ cw,
    const ushort_t* __restrict__ h0g,      // h0 for L3 (64 nodes, global)
    const ushort_t* __restrict__ pmax,     // 320 slots (L5: 0..255, L4: 256..319)
    float* __restrict__ out)
{
    __shared__ ushort_t xs[128 * 136];
    __shared__ ushort_t hnew[128 * 136];
    __shared__ ushort_t hs[128 * 136];     // h0: staged (L3), attn-written after
    __shared__ float scp[8][128];
    __shared__ float sc[128];
    __shared__ float al[4][32];
    __shared__ float smax[4][128];

    const int t = threadIdx.x;
    const int bb = blockIdx.x * 2;         // batch base (2 batch cols/block)
    const int lane = t & 63, w = t >> 6;
    const int quad = lane >> 4, l15 = lane & 15;
    const int gA = w * 16 + l15;
    const int g0 = w * 16 + quad * 4;

    s8 bwi[3][4], bwh[3][4];
    #pragma unroll
    for (int gm = 0; gm < 3; ++gm) {
        const ushort_t* wp = wihb + (size_t)(gm * 128 + gA) * 128 + quad * 8;
        #pragma unroll
        for (int s = 0; s < 4; ++s) bwi[gm][s] = *(const s8*)(wp + 32 * s);
        const ushort_t* wp2 = whhb + (size_t)(gm * 128 + gA) * 128 + quad * 8;
        #pragma unroll
        for (int s = 0; s < 4; ++s) bwh[gm][s] = *(const s8*)(wp2 + 32 * s);
    }
    float bR[4], bZ[4], biN[4], bhN[4];
    {
        float4 a = *(const float4*)(bih + g0);
        float4 b = *(const float4*)(bhh + g0);
        bR[0] = a.x + b.x; bR[1] = a.y + b.y; bR[2] = a.z + b.z; bR[3] = a.w + b.w;
        float4 c = *(const float4*)(bih + 128 + g0);
        float4 d = *(const float4*)(bhh + 128 + g0);
        bZ[0] = c.x + d.x; bZ[1] = c.y + d.y; bZ[2] = c.z + d.z; bZ[3] = c.w + d.w;
        float4 e = *(const float4*)(bih + 256 + g0);
        float4 f = *(const float4*)(bhh + 256 + g0);
        biN[0] = e.x; biN[1] = e.y; biN[2] = e.z; biN[3] = e.w;
        bhN[0] = f.x; bhN[1] = f.y; bhN[2] = f.z; bhN[3] = f.w;
    }
    s8 bsw[4];
    {
        const ushort_t* wp = swt + (size_t)gA * 128 + quad * 8;
        #pragma unroll
        for (int s = 0; s < 4; ++s) bsw[s] = *(const s8*)(wp + 32 * s);
    }
    float sb4[4], cw4[4];
    {
        float4 a = *(const float4*)(sb + g0);
        float4 b = *(const float4*)(cw + g0);
        sb4[0] = a.x; sb4[1] = a.y; sb4[2] = a.z; sb4[3] = a.w;
        cw4[0] = b.x; cw4[1] = b.y; cw4[2] = b.z; cw4[3] = b.w;
    }

    float vmax = -INFINITY;

    const int nodesA[4] = {64, 16, 4, 1};
    const int tok0A[4]  = {21, 5, 1, 0};

    for (int L = 0; L < 4; ++L) {
        const int nodes = nodesA[L], tok0 = tok0A[L];
        const int vrows = nodes * 2;
        const int R = (vrows + 15) & ~15;      // 128, 32, 16, 16
        const int mts = R >> 4;

        // ---- stage x (+h0 from global for L3): 4 thr/row, 32 shorts ----
        {
            int lr = t >> 2, c0 = (t & 3) * 32;
            if (lr < R) {
                int n = min(lr >> 1, nodes - 1);   // clamp -> dup pad rows
                int b = bb + (lr & 1);
                int tok = tokens[(tok0 + n) * 256 + b];
                const ushort_t* src = embb + (size_t)tok * 128 + c0;
                ushort_t* dst = &xs[lr * 136 + c0];
                #pragma unroll
                for (int i = 0; i < 4; ++i) *(s8*)(dst + 8 * i) = *(const s8*)(src + 8 * i);
                if (L == 0) {
                    const ushort_t* hsrc = h0g + ((size_t)n * 256 + b) * 128 + c0;
                    ushort_t* hdst = &hs[lr * 136 + c0];
                    #pragma unroll
                    for (int i = 0; i < 4; ++i) *(s8*)(hdst + 8 * i) = *(const s8*)(hsrc + 8 * i);
                }
            }
        }
        __syncthreads();

        // ---- GRU ----
        for (int mt = 0; mt < mts; ++mt) {
            const int row = mt * 16 + l15;
            const int hr = min(row >> 1, nodes - 1) * 2 + (row & 1);  // clamped h0 row
            s8 ax[4], ah[4];
            {
                const ushort_t* ap = &xs[row * 136 + quad * 8];
                #pragma unroll
                for (int s = 0; s < 4; ++s) ax[s] = *(const s8*)(ap + 32 * s);
                const ushort_t* hp = &hs[hr * 136 + quad * 8];
                #pragma unroll
                for (int s = 0; s < 4; ++s) ah[s] = *(const s8*)(hp + 32 * s);
            }
            f4 accR = (f4)0.f, accZ = (f4)0.f, accN = (f4)0.f, accNh = (f4)0.f;
            #pragma unroll
            for (int s = 0; s < 4; ++s) {
                accR = __builtin_amdgcn_mfma_f32_16x16x32_bf16(bwi[0][s], ax[s], accR, 0, 0, 0);
                accZ = __builtin_amdgcn_mfma_f32_16x16x32_bf16(bwi[1][s], ax[s], accZ, 0, 0, 0);
                accN = __builtin_amdgcn_mfma_f32_16x16x32_bf16(bwi[2][s], ax[s], accN, 0, 0, 0);
            }
            #pragma unroll
            for (int s = 0; s < 4; ++s) {
                accR  = __builtin_amdgcn_mfma_f32_16x16x32_bf16(bwh[0][s], ah[s], accR, 0, 0, 0);
                accZ  = __builtin_amdgcn_mfma_f32_16x16x32_bf16(bwh[1][s], ah[s], accZ, 0, 0, 0);
                accNh = __builtin_amdgcn_mfma_f32_16x16x32_bf16(bwh[2][s], ah[s], accNh, 0, 0, 0);
            }
            float h0v[4];
            {
                short4 h04 = *(const short4*)&hs[hr * 136 + g0];
                h0v[0] = b2f((ushort_t)h04.x); h0v[1] = b2f((ushort_t)h04.y);
                h0v[2] = b2f((ushort_t)h04.z); h0v[3] = b2f((ushort_t)h04.w);
            }
            float hv[4];
            #pragma unroll
            for (int r = 0; r < 4; ++r) {
                float rr = sigf(accR[r] + bR[r]);
                float zz = sigf(accZ[r] + bZ[r]);
                float nn = tanh_f(accN[r] + biN[r] + rr * (accNh[r] + bhN[r]));
                hv[r] = nn + zz * (h0v[r] - nn);
            }
            uint2 ov; ov.x = pk2(hv[0], hv[1]); ov.y = pk2(hv[2], hv[3]);
            *(uint2*)&hnew[row * 136 + g0] = ov;
        }
        __syncthreads();

        // ---- running max (rows >= R are stale-but-already-maxed; pads dup) ----
        {
            int col = t & 127, g = t >> 7;
            int r = (g & 1) + (g >> 1) * 64;
            #pragma unroll 4
            for (int k = 0; k < 32; ++k, r += 2)
                vmax = fmaxf(vmax, b2f(hnew[r * 136 + col]));
        }

        if (L < 3) {
            // ---- attention: siblings of parent (pj,b) = rows (4pj+k)*2+b ----
            for (int mt = 0; mt < mts; ++mt) {
                const int crow = mt * 16 + l15;
                s8 a[4];
                const ushort_t* ap = &hnew[crow * 136 + quad * 8];
                #pragma unroll
                for (int s = 0; s < 4; ++s) a[s] = *(const s8*)(ap + 32 * s);
                f4 acc = (f4)0.f;
                #pragma unroll
                for (int s = 0; s < 4; ++s)
                    acc = __builtin_amdgcn_mfma_f32_16x16x32_bf16(bsw[s], a[s], acc, 0, 0, 0);
                float part = 0.f;
                #pragma unroll
                for (int r = 0; r < 4; ++r)
                    part += tanh_f(acc[r] + sb4[r]) * cw4[r];
                part += __shfl_xor(part, 16);
                part += __shfl_xor(part, 32);
                if (quad == 0) scp[w][crow] = part;
            }
            __syncthreads();
            if (t < R) {
                float s = 0.f;
                #pragma unroll
                for (int g = 0; g < 8; ++g) s += scp[g][t];
                sc[t] = tanh_f(s);
            }
            __syncthreads();
            const int P = (nodes >> 2) * 2;    // parent rows: 32, 8, 2
            if (t < P) {
                int pj = t >> 1, b_ = t & 1;
                float s0 = sc[(4 * pj + 0) * 2 + b_], s1 = sc[(4 * pj + 1) * 2 + b_];
                float s2 = sc[(4 * pj + 2) * 2 + b_], s3 = sc[(4 * pj + 3) * 2 + b_];
                float m = fmaxf(fmaxf(s0, s1), fmaxf(s2, s3));
                float e0 = fexp2f((s0 - m) * 1.44269504f);
                float e1 = fexp2f((s1 - m) * 1.44269504f);
                float e2 = fexp2f((s2 - m) * 1.44269504f);
                float e3 = fexp2f((s3 - m) * 1.44269504f);
                float inv = frcpf(e0 + e1 + e2 + e3);
                al[0][t] = e0 * inv; al[1][t] = e1 * inv;
                al[2][t] = e2 * inv; al[3][t] = e3 * inv;
            }
            __syncthreads();
            if (t < 16 * P) {
                int bl = t >> 4, e0 = (t & 15) * 8;
                int pj = bl >> 1, b_ = bl & 1;
                float a0 = al[0][bl], a1 = al[1][bl], a2 = al[2][bl], a3 = al[3][bl];
                s8 c0v = *(const s8*)&hnew[((4 * pj + 0) * 2 + b_) * 136 + e0];
                s8 c1v = *(const s8*)&hnew[((4 * pj + 1) * 2 + b_) * 136 + e0];
                s8 c2v = *(const s8*)&hnew[((4 * pj + 2) * 2 + b_) * 136 + e0];
                s8 c3v = *(const s8*)&hnew[((4 * pj + 3) * 2 + b_) * 136 + e0];
                float o[8];
                #pragma unroll
                for (int j = 0; j < 8; ++j) {
                    o[j] = a0 * b2f((ushort_t)c0v[j]) + a1 * b2f((ushort_t)c1v[j])
                         + a2 * b2f((ushort_t)c2v[j]) + a3 * b2f((ushort_t)c3v[j]);
                }
                uint4 ovv;
                ovv.x = pk2(o[0], o[1]); ovv.y = pk2(o[2], o[3]);
                ovv.z = pk2(o[4], o[5]); ovv.w = pk2(o[6], o[7]);
                *(uint4*)&hs[bl * 136 + e0] = ovv;   // parent h0 -> hs row bl
            }
            __syncthreads();
        }
    }

    // ---- own-level max -> LDS ----
    smax[t >> 7][t & 127] = vmax;
    __syncthreads();

    // ---- final reduce over 320 global pmax slots + own levels -> out ----
    // 512 thr = 2 rows x 16 col-groups x 16 slot-chunks (16B s8 loads).
    {
        int b_ = t >> 8;              // 0..1
        int cg = (t >> 4) & 15;       // col group (8 cols)
        int ck = t & 15;              // slot chunk
        const ushort_t* base = pmax + (size_t)(bb + b_) * 128 + cg * 8;
        float v8[8];
        #pragma unroll
        for (int j = 0; j < 8; ++j) v8[j] = -INFINITY;
        for (int s = ck; s < 320; s += 16) {
            s8 c = *(const s8*)(base + (size_t)s * 32768);
            #pragma unroll
            for (int j = 0; j < 8; ++j) v8[j] = fmaxf(v8[j], b2f((ushort_t)c[j]));
        }
        #pragma unroll
        for (int m = 1; m < 16; m <<= 1) {
            #pragma unroll
            for (int j = 0; j < 8; ++j) v8[j] = fmaxf(v8[j], __shfl_xor(v8[j], m));
        }
        if (ck == 0) {
            float o[8];
            #pragma unroll
            for (int j = 0; j < 8; ++j) {
                int col = cg * 8 + j;
                float own = fmaxf(smax[b_][col], smax[b_ + 2][col]);
                o[j] = fmaxf(v8[j], own);
            }
            float* op = out + (size_t)(bb + b_) * 128 + cg * 8;
            *(float4*)op       = make_float4(o[0], o[1], o[2], o[3]);
            *(float4*)(op + 4) = make_float4(o[4], o[5], o[6], o[7]);
        }
    }
}

extern "C" void kernel_launch(void* const* d_in, const int* in_sizes, int n_in,
                              void* d_out, int out_size, void* d_ws, size_t ws_size,
                              hipStream_t stream)
{
    const int*   tokens = (const int*)d_in[0];
    const float* emb    = (const float*)d_in[1];
    const float* Wih    = (const float*)d_in[2];
    const float* Whh    = (const float*)d_in[3];
    const float* bih    = (const float*)d_in[4];
    const float* bhh    = (const float*)d_in[5];
    const float* SW     = (const float*)d_in[6];
    const float* sb     = (const float*)d_in[7];
    const float* cw     = (const float*)d_in[8];
    float* out = (float*)d_out;

    // ws layout
    ushort_t* embb = (ushort_t*)d_ws;                        // 12.8 MB
    ushort_t* wihb = embb + (size_t)EMB_N;
    ushort_t* whhb = wihb + W_N;
    ushort_t* swtb = whhb + W_N;
    ushort_t* h4   = swtb + SW_N;                            // 256n: 16.8 MB
    ushort_t* h0_4 = h4 + (size_t)256 * 32768;               // 256n
    ushort_t* h0_3 = h0_4 + (size_t)256 * 32768;             // 64n
    ushort_t* pmax = h0_3 + (size_t)64 * 32768;              // 320 slots: 21 MB

    cvt_kernel<<<(CVT_N / 4 + 255) / 256, 256, 0, stream>>>(
        emb, Wih, Whh, SW, embb, wihb, whhb, swtb);

    // L5 fused: leaf GRU + attn + sibling max -> h0_4 + pmax[0..255]
    leafattn_mfma<<<2048, 512, 0, stream>>>(
        tokens, embb, wihb, bih, bhh, swtb, sb, cw, h0_4, pmax);

    // L4 split (fusing measured worse): GRU then attn+max -> pmax[256..319]
    gru_mfma<<<512, 512, 0, stream>>>(
        tokens, embb, wihb, whhb, bih, bhh, h0_4, h4, 85);
    attnmax_mfma<<<512, 512, 0, stream>>>(h4, h0_3, pmax + (size_t)256 * 32768,
                                          swtb, sb, cw);

    // L3+L2+L1+root + final max in one kernel -> out
    tail_kernel<<<128, 512, 0, stream>>>(
        tokens, embb, wihb, whhb, bih, bhh, swtb, sb, cw,
        h0_3, pmax, out);
}